// Round 9
// baseline (22.796 us; speedup 1.0000x reference)
//
#include <hip/hip_runtime.h>
#include <stdint.h>

#define S 2048
#define B 256
#define THRESH 4

typedef unsigned long long u64;
typedef uint32_t u32;

// ws layout:
//  [0,      65536)   ptok : S*4 u64   (64 KB)  bit-packed token rows
//  [65536,  98304)   qc   : S*8 u16   (32 KB)
//  [98304, 131072)   kc   : S*8 u16   (32 KB)
//  [131072,163840)   pc   : S*8 u16   (32 KB)
//  [163840,167936)   ptab : 1024 u32  ( 4 KB)  bit-packed tables

// blocks 0..511: 4 rows each (token pack + q/k/p contribs, conn in LDS)
// blocks 512..515: table -> bitpacked u32 (256 words per block)
__global__ void prep_kernel(const int* __restrict__ tokens,
                            const int* __restrict__ conn,
                            const int* __restrict__ table,
                            u64* __restrict__ ptok,
                            uint16_t* __restrict__ qc,
                            uint16_t* __restrict__ kc,
                            uint16_t* __restrict__ pc,
                            u32* __restrict__ ptab) {
    const int bi = blockIdx.x, tid = threadIdx.x;

    if (bi >= 512) {
        const int m = (bi - 512) * 256 + tid;   // 0..1023
        const int* src = table + m * 32;
        u32 v = 0;
        #pragma unroll
        for (int b = 0; b < 32; ++b) v |= (u32)(src[b] & 1) << b;
        ptab[m] = v;
        return;
    }

    __shared__ u32 s_conn[96];
    __shared__ u64 s_row[4][4];
    const int lane = tid & 63, wave = tid >> 6;

    if (tid < 96) s_conn[tid] = (u32)conn[tid];

    const int r0 = bi * 4;
    #pragma unroll
    for (int r = 0; r < 4; ++r) {
        const int t = tokens[(r0 + r) * B + tid];
        const u64 m = __ballot(t != 0);
        if (lane == 0) { s_row[r][wave] = m; ptok[(r0 + r) * 4 + wave] = m; }
    }
    __syncthreads();

    if (tid < 32) {
        const int r = tid >> 3, h = tid & 7;
        const int i = r0 + r;
        int q = 0, k = 0, p = 0;
        #pragma unroll
        for (int n = 0; n < 12; ++n) {
            const int c = (int)s_conn[h * 12 + n];
            if (c < B) {
                q |= (int)((s_row[r][c >> 6] >> (c & 63)) & 1) << n;
            } else if (c < 2 * B) {
                const int cc = c - B;
                k |= (int)((s_row[r][cc >> 6] >> (cc & 63)) & 1) << n;
            } else {
                p |= ((i >> (c - 2 * B)) & 1) << n;
            }
        }
        qc[i * 8 + h] = (uint16_t)q;
        kc[i * 8 + h] = (uint16_t)k;
        pc[i * 8 + h] = (uint16_t)p;
    }
}

// 8 table lookups for one packed address pair (a0: heads 0-3, a1: heads 4-7)
__device__ __forceinline__ int vote8(const u32* s_tab, u64 a0, u64 a1) {
    int v = 0;
    #pragma unroll
    for (int h = 0; h < 4; ++h) {
        { u32 w = (u32)(a0 >> (16 * h + 5)) & 127;
          v += (int)((s_tab[h * 128 + w] >> ((u32)(a0 >> (16 * h)) & 31)) & 1); }
        { u32 w = (u32)(a1 >> (16 * h + 5)) & 127;
          v += (int)((s_tab[(h + 4) * 128 + w] >> ((u32)(a1 >> (16 * h)) & 31)) & 1); }
    }
    return v;
}

// one row per block; consecutive blocks pair to balanced rows (sum 2049 slots)
__launch_bounds__(256, 8)
__global__ void main_kernel(const u64* __restrict__ ptok,
                            const uint16_t* __restrict__ qc,
                            const uint16_t* __restrict__ kc,
                            const uint16_t* __restrict__ pc,
                            const u32* __restrict__ ptab,
                            int* __restrict__ out) {
    __shared__ u32 s_tab[1024];                 // 4 KB bitpacked tables
    __shared__ u64 s_red[4][5];                 // per-wave: x0..3, key

    const int b   = blockIdx.x;                 // 0..2047
    const int tid = threadIdx.x;
    const int lane = tid & 63, wave = tid >> 6;

    ((uint4*)s_tab)[tid] = ((const uint4*)ptab)[tid];
    __syncthreads();

    const int row = (b & 1) ? (2047 - (b >> 1)) : (b >> 1);
    const int n   = row + 1;

    // uniform per-block -> scalar loads
    const u64 q0 = *(const u64*)(qc + row * 8);
    const u64 q1 = *(const u64*)(qc + row * 8 + 4);

    u64 x0 = 0, x1 = 0, x2 = 0, x3 = 0;
    u32 bk = 2047u;                             // ((v+1)<<16)|(2047-j): v=-1,j=0

    const int niter = (n + 255) >> 8;
    #pragma unroll 2
    for (int it = 0; it < niter; ++it) {
        const int v = (it << 8) + tid;
        const int j = min(v, row);              // clamped lanes duplicate j=row
        const int d = row - j;

        const ulonglong2 kk = *(const ulonglong2*)(kc + j * 8);
        const ulonglong2 pp = *(const ulonglong2*)(pc + d * 8);

        // disjoint bit-fields: no carry across 16-bit head lanes
        const int vt = vote8(s_tab, q0 + kk.x + pp.x, q1 + kk.y + pp.y);

        const u32 key = ((u32)(vt + 1) << 16) | (u32)(2047 - j);
        bk = max(bk, key);                      // dup j=row keys are harmless

        if ((v <= row) & (vt >= THRESH)) {      // load tokens only when included
            const ulonglong2 t0 = *(const ulonglong2*)(ptok + j * 4);
            const ulonglong2 t1 = *(const ulonglong2*)(ptok + j * 4 + 2);
            x0 ^= t0.x; x1 ^= t0.y; x2 ^= t1.x; x3 ^= t1.y;
        }
    }

    // wave butterfly
    #pragma unroll
    for (int off = 32; off; off >>= 1) {
        bk = max(bk, (u32)__shfl_xor((int)bk, off));
        x0 ^= __shfl_xor(x0, off); x1 ^= __shfl_xor(x1, off);
        x2 ^= __shfl_xor(x2, off); x3 ^= __shfl_xor(x3, off);
    }
    if (lane == 0) {
        s_red[wave][0] = x0; s_red[wave][1] = x1;
        s_red[wave][2] = x2; s_red[wave][3] = x3;
        s_red[wave][4] = (u64)bk;
    }
    __syncthreads();

    const u32 fk = max(max((u32)s_red[0][4], (u32)s_red[1][4]),
                       max((u32)s_red[2][4], (u32)s_red[3][4]));
    const int widx = tid >> 6, bitb = tid & 63;
    const u64 xw = s_red[0][widx] ^ s_red[1][widx] ^ s_red[2][widx] ^ s_red[3][widx];

    int o;
    if ((fk >> 16) > THRESH) {                  // bestv+1 > 4 <=> bestv >= THRESH
        o = (int)((xw >> bitb) & 1);
    } else {
        const int bj = 2047 - (int)(fk & 0xFFFF);
        o = (int)((ptok[bj * 4 + widx] >> bitb) & 1);
    }
    out[row * B + tid] = o;
}

extern "C" void kernel_launch(void* const* d_in, const int* in_sizes, int n_in,
                              void* d_out, int out_size, void* d_ws, size_t ws_size,
                              hipStream_t stream) {
    const int* tokens = (const int*)d_in[0];
    const int* conn   = (const int*)d_in[1];
    const int* table  = (const int*)d_in[2];
    int* outp = (int*)d_out;

    uint8_t* ws = (uint8_t*)d_ws;
    u64*      ptok = (u64*)(ws);
    uint16_t* qcp  = (uint16_t*)(ws + 65536);
    uint16_t* kcp  = (uint16_t*)(ws + 98304);
    uint16_t* pcp  = (uint16_t*)(ws + 131072);
    u32*      ptab = (u32*)(ws + 163840);

    prep_kernel<<<516, 256, 0, stream>>>(tokens, conn, table, ptok, qcp, kcp, pcp, ptab);
    main_kernel<<<S, 256, 0, stream>>>(ptok, qcp, kcp, pcp, ptab, outp);
}

// Round 10
// 20.347 us; speedup vs baseline: 1.1204x; 1.1204x over previous
//
#include <hip/hip_runtime.h>
#include <stdint.h>

#define S 2048
#define B 256
#define THRESH 4

typedef unsigned long long u64;
typedef uint32_t u32;

// ws layout:
//  [0,      65536)   ptok : S*4 u64   (64 KB)  bit-packed token rows
//  [65536,  98304)   qc   : S*8 u16   (32 KB)
//  [98304, 131072)   kc   : S*8 u16   (32 KB)
//  [131072,163840)   pc   : S*8 u16   (32 KB)
//  [163840,167936)   ptab : 1024 u32  ( 4 KB)  bit-packed tables

// blocks 0..255: 8 rows each (token pack + q/k/p contribs, conn in LDS)
// blocks 256..259: table -> bitpacked u32 (256 words per block)
__global__ void prep_kernel(const int* __restrict__ tokens,
                            const int* __restrict__ conn,
                            const int* __restrict__ table,
                            u64* __restrict__ ptok,
                            uint16_t* __restrict__ qc,
                            uint16_t* __restrict__ kc,
                            uint16_t* __restrict__ pc,
                            u32* __restrict__ ptab) {
    const int bi = blockIdx.x, tid = threadIdx.x;

    if (bi >= 256) {
        const int m = (bi - 256) * 256 + tid;   // 0..1023
        const int* src = table + m * 32;
        u32 v = 0;
        #pragma unroll
        for (int b = 0; b < 32; ++b) v |= (u32)(src[b] & 1) << b;
        ptab[m] = v;
        return;
    }

    __shared__ u32 s_conn[96];
    __shared__ u64 s_row[8][4];
    const int lane = tid & 63, wave = tid >> 6;

    if (tid < 96) s_conn[tid] = (u32)conn[tid];

    const int r0 = bi * 8;
    #pragma unroll
    for (int r = 0; r < 8; ++r) {
        const int t = tokens[(r0 + r) * B + tid];
        const u64 m = __ballot(t != 0);
        if (lane == 0) { s_row[r][wave] = m; ptok[(r0 + r) * 4 + wave] = m; }
    }
    __syncthreads();

    if (tid < 64) {
        const int r = tid >> 3, h = tid & 7;
        const int i = r0 + r;
        int q = 0, k = 0, p = 0;
        #pragma unroll
        for (int n = 0; n < 12; ++n) {
            const int c = (int)s_conn[h * 12 + n];
            if (c < B) {
                q |= (int)((s_row[r][c >> 6] >> (c & 63)) & 1) << n;
            } else if (c < 2 * B) {
                const int cc = c - B;
                k |= (int)((s_row[r][cc >> 6] >> (cc & 63)) & 1) << n;
            } else {
                p |= ((i >> (c - 2 * B)) & 1) << n;
            }
        }
        qc[i * 8 + h] = (uint16_t)q;
        kc[i * 8 + h] = (uint16_t)k;
        pc[i * 8 + h] = (uint16_t)p;
    }
}

// 8 table lookups for one packed address pair (a0: heads 0-3, a1: heads 4-7)
__device__ __forceinline__ int vote8(const u32* s_tab, u64 a0, u64 a1) {
    int v = 0;
    #pragma unroll
    for (int h = 0; h < 4; ++h) {
        { u32 w = (u32)(a0 >> (16 * h + 5)) & 127;
          v += (int)((s_tab[h * 128 + w] >> ((u32)(a0 >> (16 * h)) & 31)) & 1); }
        { u32 w = (u32)(a1 >> (16 * h + 5)) & 127;
          v += (int)((s_tab[(h + 4) * 128 + w] >> ((u32)(a1 >> (16 * h)) & 31)) & 1); }
    }
    return v;
}

#define SLOT_LOAD(s, vv)                                                      \
    const bool isA##s = (vv) < nA;                                            \
    const int  j##s   = isA##s ? (vv) : (vv) - nA;                            \
    const int  d##s   = (isA##s ? rowA : rowB) - j##s;                        \
    const ulonglong2 kk##s = *(const ulonglong2*)(kc + j##s * 8);             \
    const ulonglong2 pp##s = *(const ulonglong2*)(pc + d##s * 8);             \
    const ulonglong2 ta##s = *(const ulonglong2*)(ptok + j##s * 4);           \
    const ulonglong2 tb##s = *(const ulonglong2*)(ptok + j##s * 4 + 2);

#define SLOT_PROC(s)                                                          \
    {                                                                         \
        const int vt = vote8(s_tab,                                           \
            (isA##s ? qA.x : qB.x) + kk##s.x + pp##s.x,                       \
            (isA##s ? qA.y : qB.y) + kk##s.y + pp##s.y);                      \
        const u32 vk = ((u32)(vt + 1) << 16) | (u32)(2047 - j##s);            \
        if (isA##s) { if (vk > bkA) bkA = vk; }                               \
        else        { if (vk > bkB) bkB = vk; }                               \
        if (vt >= THRESH) {                                                   \
            if (isA##s) { ax0 ^= ta##s.x; ax1 ^= ta##s.y;                     \
                          ax2 ^= tb##s.x; ax3 ^= tb##s.y; }                   \
            else        { bx0 ^= ta##s.x; bx1 ^= ta##s.y;                     \
                          bx2 ^= tb##s.x; bx3 ^= tb##s.y; }                   \
        }                                                                     \
    }

__launch_bounds__(256)
__global__ void main_kernel(const u64* __restrict__ ptok,
                            const uint16_t* __restrict__ qc,
                            const uint16_t* __restrict__ kc,
                            const uint16_t* __restrict__ pc,
                            const u32* __restrict__ ptab,
                            int* __restrict__ out) {
    __shared__ u32 s_tab[1024];                 // 4 KB bitpacked tables
    __shared__ u64 s_part[8][256];              // 16 KB xor staging
    __shared__ u64 s_p2[8][32];
    __shared__ u64 s_fin[8];
    __shared__ u64 s_kred[4];

    const int b   = blockIdx.x;                 // 0..1023
    const int tid = threadIdx.x;
    const int lane = tid & 63, wave = tid >> 6;

    ((uint4*)s_tab)[tid] = ((const uint4*)ptab)[tid];
    __syncthreads();

    // rows: pair (2046-b, b) = exactly 2048 slots; block 1023 takes {2047,1023}
    const int rowA = (b == 1023) ? 2047 : 2046 - b;
    const int rowB = (b == 1023) ? 1023 : b;
    const int nA    = rowA + 1;
    const int total = nA + rowB + 1;            // 2048 (3072 for b==1023)
    const int niter = total >> 9;               // 4 or 6 — always even

    const ulonglong2 qA = *(const ulonglong2*)(qc + rowA * 8);
    const ulonglong2 qB = *(const ulonglong2*)(qc + rowB * 8);

    u64 ax0=0, ax1=0, ax2=0, ax3=0;
    u64 bx0=0, bx1=0, bx2=0, bx3=0;
    u32 bkA = 2047u, bkB = 2047u;               // ((v+1)<<16)|(2047-j), init v=-1,j=0

    for (int it = 0; it < niter; it += 2) {     // 2x unroll: 4 slots in flight
        const int v0 = (it << 9) + tid;
        const int v1 = v0 + 256;
        const int v2 = v0 + 512;
        const int v3 = v0 + 768;

        SLOT_LOAD(0, v0)
        SLOT_LOAD(1, v1)
        SLOT_LOAD(2, v2)
        SLOT_LOAD(3, v3)

        SLOT_PROC(0)
        SLOT_PROC(1)
        SLOT_PROC(2)
        SLOT_PROC(3)
    }

    // ---- reduction: keys via tiny butterfly, xors via staged LDS tree ----
    #pragma unroll
    for (int off = 32; off; off >>= 1) {
        bkA = max(bkA, (u32)__shfl_xor((int)bkA, off));
        bkB = max(bkB, (u32)__shfl_xor((int)bkB, off));
    }

    s_part[0][tid] = ax0; s_part[1][tid] = ax1; s_part[2][tid] = ax2; s_part[3][tid] = ax3;
    s_part[4][tid] = bx0; s_part[5][tid] = bx1; s_part[6][tid] = bx2; s_part[7][tid] = bx3;
    if (lane == 0) s_kred[wave] = ((u64)bkA << 32) | bkB;
    __syncthreads();

    {   // stage 1: 8 words x 32 chunks
        const int w = tid >> 5, c = tid & 31;
        u64 x = s_part[w][c]       ^ s_part[w][c + 32]  ^ s_part[w][c + 64]  ^ s_part[w][c + 96]
              ^ s_part[w][c + 128] ^ s_part[w][c + 160] ^ s_part[w][c + 192] ^ s_part[w][c + 224];
        s_p2[w][c] = x;
    }
    __syncthreads();
    if (tid < 64) {                             // stage 2: fold 32 -> 1 per word
        const int w = tid >> 3, c = tid & 7;
        u64 x = s_p2[w][c] ^ s_p2[w][c + 8] ^ s_p2[w][c + 16] ^ s_p2[w][c + 24];
        x ^= __shfl_xor(x, 4); x ^= __shfl_xor(x, 2); x ^= __shfl_xor(x, 1);
        if (c == 0) s_fin[w] = x;
    }
    __syncthreads();

    const u32 fkA = max(max((u32)(s_kred[0] >> 32), (u32)(s_kred[1] >> 32)),
                        max((u32)(s_kred[2] >> 32), (u32)(s_kred[3] >> 32)));
    const u32 fkB = max(max((u32)s_kred[0], (u32)s_kred[1]),
                        max((u32)s_kred[2], (u32)s_kred[3]));

    const int widx = tid >> 6, bitb = tid & 63;
    int oA, oB;
    if ((fkA >> 16) > THRESH) {                 // bestv+1 > 4 <=> bestv >= THRESH
        oA = (int)((s_fin[widx] >> bitb) & 1);
    } else {
        const int bj = 2047 - (int)(fkA & 0xFFFF);
        oA = (int)((ptok[bj * 4 + widx] >> bitb) & 1);
    }
    if ((fkB >> 16) > THRESH) {
        oB = (int)((s_fin[4 + widx] >> bitb) & 1);
    } else {
        const int bj = 2047 - (int)(fkB & 0xFFFF);
        oB = (int)((ptok[bj * 4 + widx] >> bitb) & 1);
    }
    out[rowA * B + tid] = oA;
    out[rowB * B + tid] = oB;
}

extern "C" void kernel_launch(void* const* d_in, const int* in_sizes, int n_in,
                              void* d_out, int out_size, void* d_ws, size_t ws_size,
                              hipStream_t stream) {
    const int* tokens = (const int*)d_in[0];
    const int* conn   = (const int*)d_in[1];
    const int* table  = (const int*)d_in[2];
    int* outp = (int*)d_out;

    uint8_t* ws = (uint8_t*)d_ws;
    u64*      ptok = (u64*)(ws);
    uint16_t* qcp  = (uint16_t*)(ws + 65536);
    uint16_t* kcp  = (uint16_t*)(ws + 98304);
    uint16_t* pcp  = (uint16_t*)(ws + 131072);
    u32*      ptab = (u32*)(ws + 163840);

    prep_kernel<<<260, 256, 0, stream>>>(tokens, conn, table, ptok, qcp, kcp, pcp, ptab);
    main_kernel<<<S / 2, 256, 0, stream>>>(ptok, qcp, kcp, pcp, ptab, outp);
}